// Round 1
// baseline (136.776 us; speedup 1.0000x reference)
//
#include <hip/hip_runtime.h>

#define NB    256
#define UNITS 1024
#define EDIM  1024
#define MEM   128

// d_out layout (floats): output[256*1024] | new_M_key[256*128*1024] | new_M_value[256*128*1024]
#define OUT_OFF 0
#define KEY_OFF (NB * UNITS)
#define VAL_OFF (KEY_OFF + (size_t)NB * MEM * UNITS)

// ---------------------------------------------------------------------------
// Fused kernel: one block per batch.
//   Phase A: logits[m] = dot(M_key[b,m,:], h_t[b,:])  +  new_M_key[b,m-1,:] = M_key[b,m,:]
//   Phase B: at = softmax(logits)
//   Phase C: output[b,:] = sum_m at[m]*M_value[b,m,:] +  new_M_value[b,m-1,:] = M_value[b,m,:]
// Each big tensor read once, written once. 1024 threads = 16 waves.
// ---------------------------------------------------------------------------
__global__ __launch_bounds__(1024) void k_fused(
    const float* __restrict__ inputs, const float* __restrict__ M_key,
    const float* __restrict__ M_value, float* __restrict__ out)
{
    __shared__ __align__(16) float h_s[UNITS];
    __shared__ float lg_s[MEM];
    __shared__ float at_s[MEM];
    __shared__ __align__(16) float red_s[4][UNITS];

    const int b    = blockIdx.x;
    const int tid  = threadIdx.x;
    const int wave = tid >> 6;
    const int lane = tid & 63;

    // stage h_t (last 1024 cols of inputs row b)
    h_s[tid] = inputs[(size_t)b * (EDIM + UNITS) + EDIM + tid];
    __syncthreads();

    // ---------------- Phase A: M_key pass ----------------
    {
        const float* mbase = M_key + (size_t)b * (MEM * UNITS);
        float*       dbase = out + KEY_OFF + (size_t)b * (MEM * UNITS);

        const float4 h0 = *(const float4*)(&h_s[lane * 4]);
        const float4 h1 = *(const float4*)(&h_s[lane * 4 + 256]);
        const float4 h2 = *(const float4*)(&h_s[lane * 4 + 512]);
        const float4 h3 = *(const float4*)(&h_s[lane * 4 + 768]);

        #pragma unroll 2
        for (int r = 0; r < 8; ++r) {
            const int m = wave * 8 + r;
            const float* mrow = mbase + (size_t)m * UNITS + lane * 4;
            float4 v0 = *(const float4*)(mrow);
            float4 v1 = *(const float4*)(mrow + 256);
            float4 v2 = *(const float4*)(mrow + 512);
            float4 v3 = *(const float4*)(mrow + 768);

            float acc = v0.x * h0.x + v0.y * h0.y + v0.z * h0.z + v0.w * h0.w
                      + v1.x * h1.x + v1.y * h1.y + v1.z * h1.z + v1.w * h1.w
                      + v2.x * h2.x + v2.y * h2.y + v2.z * h2.z + v2.w * h2.w
                      + v3.x * h3.x + v3.y * h3.y + v3.z * h3.z + v3.w * h3.w;
            #pragma unroll
            for (int off = 32; off > 0; off >>= 1)
                acc += __shfl_xor(acc, off);
            if (lane == 0) lg_s[m] = acc;

            if (m > 0) {
                float* drow = dbase + (size_t)(m - 1) * UNITS + lane * 4;
                *(float4*)(drow)       = v0;
                *(float4*)(drow + 256) = v1;
                *(float4*)(drow + 512) = v2;
                *(float4*)(drow + 768) = v3;
            }
        }
    }
    __syncthreads();

    // ---------------- Phase B: softmax over 128 logits (wave 0) ----------------
    if (wave == 0) {
        float l0 = lg_s[lane], l1 = lg_s[lane + 64];
        float mx = fmaxf(l0, l1);
        #pragma unroll
        for (int off = 32; off > 0; off >>= 1)
            mx = fmaxf(mx, __shfl_xor(mx, off));
        float e0 = __expf(l0 - mx), e1 = __expf(l1 - mx);
        float s = e0 + e1;
        #pragma unroll
        for (int off = 32; off > 0; off >>= 1)
            s += __shfl_xor(s, off);
        float inv = 1.0f / s;
        at_s[lane]      = e0 * inv;
        at_s[lane + 64] = e1 * inv;
    }
    __syncthreads();

    // ---------------- Phase C: M_value pass ----------------
    {
        const int rc  = wave >> 2;          // row chunk: 32 rows
        const int cc  = wave & 3;           // col chunk: 256 cols
        const int col = cc * 256 + lane * 4;
        const float* vbase = M_value + (size_t)b * (MEM * UNITS) + col;
        float*       dbase = out + VAL_OFF + (size_t)b * (MEM * UNITS) + col;

        float4 acc = {0.f, 0.f, 0.f, 0.f};
        #pragma unroll 4
        for (int r = 0; r < 32; ++r) {
            const int m = rc * 32 + r;
            float4 v = *(const float4*)(vbase + (size_t)m * UNITS);
            const float w = at_s[m];
            acc.x += w * v.x; acc.y += w * v.y; acc.z += w * v.z; acc.w += w * v.w;
            if (m > 0)
                *(float4*)(dbase + (size_t)(m - 1) * UNITS) = v;
        }
        *(float4*)(&red_s[rc][cc * 256 + lane * 4]) = acc;
    }
    __syncthreads();

    if (wave < 4) {
        const int col = wave * 256 + lane * 4;
        float4 a0 = *(const float4*)(&red_s[0][col]);
        float4 a1 = *(const float4*)(&red_s[1][col]);
        float4 a2 = *(const float4*)(&red_s[2][col]);
        float4 a3 = *(const float4*)(&red_s[3][col]);
        float4 s;
        s.x = a0.x + a1.x + a2.x + a3.x;
        s.y = a0.y + a1.y + a2.y + a3.y;
        s.z = a0.z + a1.z + a2.z + a3.z;
        s.w = a0.w + a1.w + a2.w + a3.w;
        *(float4*)(out + OUT_OFF + (size_t)b * UNITS + col) = s;
    }
}

// ---------------------------------------------------------------------------
// fp32 SIMT GEMM: C[w] = e_t(256x1024, lda=2048) @ W[w](1024x1024)
// 64x64 tile, 256 threads, 4x4 per thread, K-tile 32, split-K over blockIdx.y.
// Writes partials to ws (or direct to out row 127 when direct=1, ksplit must be 1).
// ---------------------------------------------------------------------------
#define TK 32

__global__ __launch_bounds__(256) void k_gemm(
    const float* __restrict__ inputs,
    const float* __restrict__ W_key, const float* __restrict__ W_value,
    float* __restrict__ partials, float* __restrict__ out,
    int ksplit, int direct)
{
    const int tile = blockIdx.x;        // 0..63
    const int mt = tile >> 4;           // 0..3
    const int nt = tile & 15;           // 0..15
    const int kc = blockIdx.y;          // 0..ksplit-1
    const int w  = blockIdx.z;          // 0..1
    const float* Wm = w ? W_value : W_key;

    __shared__ __align__(16) float As[TK][68];   // [k][m], padded
    __shared__ __align__(16) float Bs[TK][64];   // [k][n]

    const int tid = threadIdx.x;
    const int ty = tid >> 4, tx = tid & 15;

    float acc[4][4] = {};

    const int klen = EDIM / ksplit;
    const int k0   = kc * klen;

    for (int kt = k0; kt < k0 + klen; kt += TK) {
        #pragma unroll
        for (int q = 0; q < 2; ++q) {
            const int f  = tid * 2 + q;          // 0..511
            const int ar = f >> 3;               // 0..63
            const int ac = (f & 7) << 2;         // 0..28
            float4 a = *(const float4*)(inputs + (size_t)(mt * 64 + ar) * (EDIM + UNITS) + kt + ac);
            As[ac + 0][ar] = a.x;
            As[ac + 1][ar] = a.y;
            As[ac + 2][ar] = a.z;
            As[ac + 3][ar] = a.w;
        }
        #pragma unroll
        for (int q = 0; q < 2; ++q) {
            const int f  = tid * 2 + q;
            const int br = f >> 4;               // 0..31
            const int bc = (f & 15) << 2;        // 0..60
            *(float4*)(&Bs[br][bc]) =
                *(const float4*)(Wm + (size_t)(kt + br) * UNITS + nt * 64 + bc);
        }
        __syncthreads();

        #pragma unroll
        for (int kk = 0; kk < TK; ++kk) {
            const float4 av = *(const float4*)(&As[kk][ty * 4]);
            const float4 bv = *(const float4*)(&Bs[kk][tx * 4]);
            acc[0][0] += av.x * bv.x; acc[0][1] += av.x * bv.y; acc[0][2] += av.x * bv.z; acc[0][3] += av.x * bv.w;
            acc[1][0] += av.y * bv.x; acc[1][1] += av.y * bv.y; acc[1][2] += av.y * bv.z; acc[1][3] += av.y * bv.w;
            acc[2][0] += av.z * bv.x; acc[2][1] += av.z * bv.y; acc[2][2] += av.z * bv.z; acc[2][3] += av.z * bv.w;
            acc[3][0] += av.w * bv.x; acc[3][1] += av.w * bv.y; acc[3][2] += av.w * bv.z; acc[3][3] += av.w * bv.w;
        }
        __syncthreads();
    }

    if (direct) {
        float* dst = out + (w ? VAL_OFF : KEY_OFF) + (size_t)(MEM - 1) * UNITS;
        #pragma unroll
        for (int i = 0; i < 4; ++i) {
            float4 v = {acc[i][0], acc[i][1], acc[i][2], acc[i][3]};
            *(float4*)(dst + (size_t)(mt * 64 + ty * 4 + i) * (MEM * UNITS) + nt * 64 + tx * 4) = v;
        }
    } else {
        float* P = partials + ((size_t)(w * ksplit + kc) * 64 + tile) * 4096;
        #pragma unroll
        for (int i = 0; i < 4; ++i) {
            float4 v = {acc[i][0], acc[i][1], acc[i][2], acc[i][3]};
            *(float4*)(P + (ty * 4 + i) * 64 + tx * 4) = v;
        }
    }
}

// Sum split-K partials and scatter into new_M_key/new_M_value row 127.
__global__ __launch_bounds__(256) void k_gemm_reduce(
    const float* __restrict__ partials, float* __restrict__ out, int ksplit)
{
    const int idx = blockIdx.x * 256 + threadIdx.x;  // 0 .. 2*256*1024-1
    const int w  = idx >> 18;
    const int rn = idx & ((1 << 18) - 1);
    const int r  = rn >> 10;
    const int n  = rn & 1023;
    const int mt = r >> 6, ri = r & 63;
    const int nt = n >> 6, ni = n & 63;

    const float* P = partials + ((size_t)(w * ksplit) * 64 + (mt * 16 + nt)) * 4096
                   + ri * 64 + ni;
    float s = 0.f;
    for (int kc = 0; kc < ksplit; ++kc)
        s += P[(size_t)kc * 64 * 4096];

    out[(w ? VAL_OFF : KEY_OFF) + (size_t)r * (MEM * UNITS) + (size_t)(MEM - 1) * UNITS + n] = s;
}

extern "C" void kernel_launch(void* const* d_in, const int* in_sizes, int n_in,
                              void* d_out, int out_size, void* d_ws, size_t ws_size,
                              hipStream_t stream)
{
    const float* inputs  = (const float*)d_in[0];
    const float* M_key   = (const float*)d_in[1];
    const float* M_value = (const float*)d_in[2];
    const float* W_key   = (const float*)d_in[3];
    const float* W_value = (const float*)d_in[4];
    float* out      = (float*)d_out;
    float* partials = (float*)d_ws;

    const size_t need4 = (size_t)2 * 4 * 64 * 4096 * sizeof(float); // 8.4 MB
    const size_t need1 = (size_t)2 * 1 * 64 * 4096 * sizeof(float); // 2.1 MB
    int ksplit, direct;
    if (ws_size >= need4)      { ksplit = 4; direct = 0; }
    else if (ws_size >= need1) { ksplit = 1; direct = 0; }
    else                       { ksplit = 1; direct = 1; }

    hipLaunchKernelGGL(k_fused, dim3(NB), dim3(1024), 0, stream,
                       inputs, M_key, M_value, out);
    hipLaunchKernelGGL(k_gemm, dim3(64, ksplit, 2), dim3(256), 0, stream,
                       inputs, W_key, W_value, partials, out, ksplit, direct);
    if (!direct)
        hipLaunchKernelGGL(k_gemm_reduce, dim3(2048), dim3(256), 0, stream,
                           partials, out, ksplit);
}